// Round 4
// baseline (1015.225 us; speedup 1.0000x reference)
//
#include <hip/hip_runtime.h>
#include <hip/hip_bf16.h>

// Problem constants
#define B_   8192
#define S_   1152
#define G_   576
#define F_   16
#define L_   24
#define NP_  576
#define KA   1856      // padded K of A / Wt (29 * 64)
#define NCOL 9216      // F*G
#define KV   1984      // KA + 128 (virtual K incl. loop-weight blocks)

typedef float f32x4 __attribute__((ext_vector_type(4)));
typedef short short8_t __attribute__((ext_vector_type(8)));

// ---- bf16 helpers (RNE) ----
__device__ __forceinline__ short f2bf(float v) {
  unsigned u = __float_as_uint(v);
  unsigned r = (u + 0x7fffu + ((u >> 16) & 1u)) >> 16;
  return (short)r;
}
__device__ __forceinline__ float bf2f(short s) {
  return __uint_as_float(((unsigned)(unsigned short)s) << 16);
}

__device__ __forceinline__ float log_cosh_f(float t) {
  float a = fabsf(t);
  return a + __logf(1.f + __expf(-2.f * a)) - 0.6931471805599453f;
}

__device__ __forceinline__ float wave_sum(float v) {
  #pragma unroll
  for (int d = 1; d < 64; d <<= 1) v += __shfl_xor(v, d, 64);
  return v;
}

__device__ __forceinline__ void load_lds16(const void* g, void* l) {
  __builtin_amdgcn_global_load_lds(
      (const __attribute__((address_space(1))) void*)g,
      (__attribute__((address_space(3))) void*)l, 16, 0, 0);
}

// ============================================================
// Kernel 1: build A (bf16 features) + bias -> out[b]
// A row layout (K = 1856):
//  [0,1152)    x
//  [1152,1728) cv0
//  [1728,1752) cv1_hi   [1752,1776) cv1_lo   [1776,1792) zero
//  [1792,1816) cv2_hi   [1816,1840) cv2_lo   [1840,1856) zero
// ============================================================
__global__ __launch_bounds__(256) void build_a_kernel(
    const float* __restrict__ x, const float* __restrict__ vb,
    const float* __restrict__ cb0, const float* __restrict__ cb1,
    const float* __restrict__ cb2,
    const int* __restrict__ idx0, const int* __restrict__ idx1,
    const int* __restrict__ idx2,
    short* __restrict__ A, float* __restrict__ out) {
  int b = blockIdx.x, t = threadIdx.x;
  __shared__ float xs[S_];
  __shared__ float red[20];
  float se = 0.f, so = 0.f, s0 = 0.f, s1 = 0.f, s2 = 0.f;
  const float* xr = x + (size_t)b * S_;
  short* Ar = A + (size_t)b * KA;

  for (int i = t; i < S_; i += 256) {
    float v = xr[i];
    xs[i] = v;
    Ar[i] = f2bf(v);
    if (i & 1) so += v; else se += v;
  }
  __syncthreads();

  for (int c = t; c < NP_; c += 256) {
    const int* q = idx0 + c * 4;
    float p = xs[q[0]] * xs[q[1]] * xs[q[2]] * xs[q[3]];
    s0 += p;
    Ar[S_ + c] = f2bf(p);
  }
  if (t < L_) {
    const int* q = idx1 + t * L_;
    float p = 1.f;
    #pragma unroll
    for (int j = 0; j < L_; ++j) p *= xs[q[j]];
    s1 = p;
    short hi = f2bf(p);
    Ar[1728 + t] = hi;
    Ar[1752 + t] = f2bf(p - bf2f(hi));
  }
  if (t >= 32 && t < 32 + L_) {
    int l = t - 32;
    const int* q = idx2 + l * L_;
    float p = 1.f;
    #pragma unroll
    for (int j = 0; j < L_; ++j) p *= xs[q[j]];
    s2 = p;
    short hi = f2bf(p);
    Ar[1792 + l] = hi;
    Ar[1816 + l] = f2bf(p - bf2f(hi));
  }
  if (t >= 64 && t < 80) Ar[1776 + (t - 64)] = 0;
  if (t >= 80 && t < 96) Ar[1840 + (t - 80)] = 0;

  se = wave_sum(se); so = wave_sum(so);
  s0 = wave_sum(s0); s1 = wave_sum(s1); s2 = wave_sum(s2);
  int w = t >> 6;
  if ((t & 63) == 0) {
    red[w] = se; red[4 + w] = so; red[8 + w] = s0;
    red[12 + w] = s1; red[16 + w] = s2;
  }
  __syncthreads();
  if (t == 0) {
    float a  = red[0] + red[1] + red[2] + red[3];
    float bb = red[4] + red[5] + red[6] + red[7];
    float c0 = red[8] + red[9] + red[10] + red[11];
    float c1 = red[12] + red[13] + red[14] + red[15];
    float c2 = red[16] + red[17] + red[18] + red[19];
    out[b] = vb[0] * a + vb[1] * bb + cb0[0] * c0 + cb1[0] * c1 + cb2[0] * c2;
  }
}

// ============================================================
// Kernel 2: gather weights.
// Wt[n][k], n = g*16 + f, k in [0,KA). Wlt[n][0:64) = loop0 block,
// Wlt[n][64:128) = loop1 block.
// ============================================================
__global__ __launch_bounds__(256) void build_w_kernel(
    const float* __restrict__ symm_kernel, const int* __restrict__ symmetries,
    const float* __restrict__ c0k, const int* __restrict__ c0s,
    const float* __restrict__ c1k, const int* __restrict__ c1s,
    const float* __restrict__ c2k, const int* __restrict__ c2s,
    const float* __restrict__ l0k, const float* __restrict__ l1k,
    short* __restrict__ Wt, short* __restrict__ Wlt) {
  const int CHUNKS = KV / 8;  // 248
  int t = blockIdx.x * 256 + threadIdx.x;
  int n = t / CHUNKS;
  if (n >= NCOL) return;
  int ch = t - n * CHUNKS;
  int g = n >> 4, f = n & 15;
  int k0 = ch * 8;
  short8_t pack;
  #pragma unroll
  for (int j = 0; j < 8; ++j) {
    int k = k0 + j;
    float val;
    if (k < 1152) {
      val = symm_kernel[f * S_ + symmetries[g * S_ + k]];
    } else if (k < 1728) {
      int c = k - 1152;
      val = c0k[f * NP_ + c0s[g * NP_ + c]];
    } else if (k < 1792) {
      int c = k - 1728;
      val = (c < 48) ? c1k[f * L_ + c1s[g * L_ + (c < 24 ? c : c - 24)]] : 0.f;
    } else if (k < 1856) {
      int c = k - 1792;
      val = (c < 48) ? c2k[f * L_ + c2s[g * L_ + (c < 24 ? c : c - 24)]] : 0.f;
    } else if (k < 1920) {
      int c = k - 1856;
      val = (c < 48) ? l0k[f * L_ + c1s[g * L_ + (c < 24 ? c : c - 24)]] : 0.f;
    } else {
      int c = k - 1920;
      val = (c < 48) ? l1k[f * L_ + c2s[g * L_ + (c < 24 ? c : c - 24)]] : 0.f;
    }
    pack[j] = f2bf(val);
  }
  if (k0 < KA) *(short8_t*)(Wt + (size_t)n * KA + k0) = pack;
  else         *(short8_t*)(Wlt + (size_t)n * 128 + (k0 - KA)) = pack;
}

// ============================================================
// Kernel 3: fused GEMM + log_cosh reduction.
// 128x128 tile, BK=64, 4 waves (2x2), 16x16x32 bf16 MFMA.
// - dbuf LDS prefetch (1 barrier/K-step)
// - XOR chunk swizzle (linear LDS dest, pre-swizzled global source,
//   matching XOR on ds_read) -> 0 bank conflicts (verified r2)
// - XCD supertile mapping: xcd = bid&7 owns m-stripe [8k,8k+8),
//   walks 8x8 supertiles along n -> ~7.6 MB working set per XCD L2
// NOTE: plain __launch_bounds__(256): the (256,2) variant made the
// allocator clamp to 128 VGPR and spill ~1 GB of scratch (r2 counters).
// ============================================================
__global__ __launch_bounds__(256) void gemm_fused(
    const short* __restrict__ A, const short* __restrict__ Wt,
    const short* __restrict__ Wlt,
    const float* __restrict__ hidden_bias, const float* __restrict__ l0hb,
    const float* __restrict__ l1hb, float* __restrict__ out) {
  __shared__ short Als[2][128 * 64];
  __shared__ short Bls[2][128 * 64];
  const int tid = threadIdx.x;
  const int w = tid >> 6, lane = tid & 63;
  const int wm = w >> 1, wn = w & 1;
  const int lr = lane & 15, lg = lane >> 4;

  // XCD-aware tile mapping (perf-only heuristic, bijective: 8*576 = 4608)
  const int bid = blockIdx.x;
  const int xcd = bid & 7;
  const int idx = bid >> 3;         // 0..575
  const int st  = idx >> 6;         // supertile column 0..8
  const int u   = idx & 63;
  const int m0 = (xcd * 8 + (u & 7)) * 128;
  const int n0 = (st * 8 + (u >> 3)) * 128;

  // staging geometry: chunk p = i*256 + tid -> row = i*32 + (tid>>3), slot = tid&7
  const int srow = tid >> 3, sslot = tid & 7;
  const int scol = (sslot ^ (srow & 7)) * 16;  // pre-swizzled source byte offset

  f32x4 acc[4][4];
  float rs[4][4];
  #pragma unroll
  for (int i = 0; i < 4; ++i)
    #pragma unroll
    for (int j = 0; j < 4; ++j) {
      #pragma unroll
      for (int q = 0; q < 4; ++q) acc[i][j][q] = 0.f;
      rs[i][j] = 0.f;
    }

  const char* Abase = (const char*)A + (size_t)m0 * (KA * 2);
  const char* Wbase = (const char*)Wt + (size_t)n0 * (KA * 2);
  const char* Lbase = (const char*)Wlt + (size_t)n0 * 256;

  auto stage = [&](int buf, size_t aOff, const char* bSrc, size_t bStride, size_t bOff) {
    #pragma unroll
    for (int i = 0; i < 4; ++i) {
      int row = i * 32 + srow;
      load_lds16(Abase + (size_t)row * (KA * 2) + aOff + scol,
                 (char*)Als[buf] + (i * 256 + w * 64) * 16);
      load_lds16(bSrc + (size_t)row * bStride + bOff + scol,
                 (char*)Bls[buf] + (i * 256 + w * 64) * 16);
    }
  };

  // swizzled bf16 index for fragment read: row*64 + ((chunk ^ (row&7)) * 8)
  auto compute = [&](int buf) {
    #pragma unroll
    for (int kk = 0; kk < 2; ++kk) {
      short8_t af[4], wf[4];
      #pragma unroll
      for (int mi = 0; mi < 4; ++mi) {
        int row = wm * 64 + mi * 16 + lr;
        af[mi] = *(const short8_t*)&Als[buf][row * 64 + (((kk * 4 + lg) ^ (lr & 7)) * 8)];
      }
      #pragma unroll
      for (int ni = 0; ni < 4; ++ni) {
        int row = wn * 64 + ni * 16 + lr;
        wf[ni] = *(const short8_t*)&Bls[buf][row * 64 + (((kk * 4 + lg) ^ (lr & 7)) * 8)];
      }
      #pragma unroll
      for (int mi = 0; mi < 4; ++mi)
        #pragma unroll
        for (int ni = 0; ni < 4; ++ni)
          acc[mi][ni] = __builtin_amdgcn_mfma_f32_16x16x32_bf16(af[mi], wf[ni], acc[mi][ni], 0, 0, 0);
    }
  };

  // ---- main K loop: prologue stage + 28 prefetched steps + tail compute ----
  stage(0, 0, Wbase, (size_t)(KA * 2), 0);
  __syncthreads();
  int cur = 0;
  for (int s = 0; s < 28; ++s) {
    stage(cur ^ 1, (size_t)(s + 1) * 128, Wbase, (size_t)(KA * 2), (size_t)(s + 1) * 128);
    compute(cur);
    __syncthreads();   // drains vmcnt (next buf ready) + guards cur reuse
    cur ^= 1;
  }
  compute(cur);

  // theta epilogue
  {
    float hb = hidden_bias[lr];  // f = col & 15 = lr
    #pragma unroll
    for (int mi = 0; mi < 4; ++mi)
      #pragma unroll
      for (int i = 0; i < 4; ++i) {
        float s = 0.f;
        #pragma unroll
        for (int ni = 0; ni < 4; ++ni) s += log_cosh_f(acc[mi][ni][i] + hb);
        rs[mi][i] += s;
      }
  }
  __syncthreads();  // all waves done with LDS before loop-pass staging

  // loop-correlator passes: K-block of cv1 (aOff 1728) with Wlt[:,0:64),
  // K-block of cv2 (aOff 1792) with Wlt[:,64:128)
  #pragma unroll
  for (int pass = 0; pass < 2; ++pass) {
    #pragma unroll
    for (int i = 0; i < 4; ++i)
      #pragma unroll
      for (int j = 0; j < 4; ++j)
        #pragma unroll
        for (int q = 0; q < 4; ++q) acc[i][j][q] = 0.f;

    stage(0, (size_t)(1728 + pass * 64) * 2, Lbase, 256, (size_t)pass * 128);
    __syncthreads();
    compute(0);

    float lb = (pass == 0 ? l0hb : l1hb)[lr];
    #pragma unroll
    for (int mi = 0; mi < 4; ++mi)
      #pragma unroll
      for (int i = 0; i < 4; ++i) {
        float s = 0.f;
        #pragma unroll
        for (int ni = 0; ni < 4; ++ni) s += log_cosh_f(acc[mi][ni][i] + lb);
        rs[mi][i] += s;
      }
    __syncthreads();
  }

  // reduce across the 16 lanes that share each row, then atomicAdd
  #pragma unroll
  for (int mi = 0; mi < 4; ++mi)
    #pragma unroll
    for (int i = 0; i < 4; ++i) {
      float v = rs[mi][i];
      v += __shfl_xor(v, 1, 64);
      v += __shfl_xor(v, 2, 64);
      v += __shfl_xor(v, 4, 64);
      v += __shfl_xor(v, 8, 64);
      if (lr == 0) atomicAdd(&out[m0 + wm * 64 + mi * 16 + lg * 4 + i], v);
    }
}

// ============================================================
extern "C" void kernel_launch(void* const* d_in, const int* in_sizes, int n_in,
                              void* d_out, int out_size, void* d_ws, size_t ws_size,
                              hipStream_t stream) {
  const float* x            = (const float*)d_in[0];
  const float* hidden_bias  = (const float*)d_in[1];
  const float* symm_kernel  = (const float*)d_in[2];
  const float* visible_bias = (const float*)d_in[3];
  const float* corr0_bias   = (const float*)d_in[4];
  const float* corr0_kernel = (const float*)d_in[5];
  const float* corr1_bias   = (const float*)d_in[6];
  const float* corr1_kernel = (const float*)d_in[7];
  const float* corr2_bias   = (const float*)d_in[8];
  const float* corr2_kernel = (const float*)d_in[9];
  const float* l0hb         = (const float*)d_in[10];
  const float* l0k          = (const float*)d_in[11];
  const float* l1hb         = (const float*)d_in[12];
  const float* l1k          = (const float*)d_in[13];
  const int* symmetries     = (const int*)d_in[14];
  const int* idx0           = (const int*)d_in[15];
  const int* c0s            = (const int*)d_in[16];
  const int* idx1           = (const int*)d_in[17];
  const int* c1s            = (const int*)d_in[18];
  const int* idx2           = (const int*)d_in[19];
  const int* c2s            = (const int*)d_in[20];

  // workspace layout
  short* A   = (short*)d_ws;                                  // 8192*1856*2   = 30,408,704 B
  short* Wt  = (short*)((char*)d_ws + 30408704);              // 9216*1856*2   = 34,209,792 B
  short* Wlt = (short*)((char*)d_ws + 64618496);              // 9216*128*2    =  2,359,296 B
  float* out = (float*)d_out;

  build_a_kernel<<<B_, 256, 0, stream>>>(x, visible_bias, corr0_bias, corr1_bias,
                                         corr2_bias, idx0, idx1, idx2, A, out);
  build_w_kernel<<<(NCOL * (KV / 8)) / 256, 256, 0, stream>>>(
      symm_kernel, symmetries, corr0_kernel, c0s, corr1_kernel, c1s,
      corr2_kernel, c2s, l0k, l1k, Wt, Wlt);
  gemm_fused<<<4608, 256, 0, stream>>>(
      A, Wt, Wlt, hidden_bias, l0hb, l1hb, out);
}

// Round 7
// 893.808 us; speedup vs baseline: 1.1358x; 1.1358x over previous
//
#include <hip/hip_runtime.h>
#include <hip/hip_bf16.h>

// Problem constants
#define B_   8192
#define S_   1152
#define G_   576
#define F_   16
#define L_   24
#define NP_  576
#define KA   1856      // padded K of A / Wt (29 * 64)
#define NCOL 9216      // F*G
#define KV   1984      // KA + 128 (virtual K incl. loop-weight blocks)

typedef float f32x4 __attribute__((ext_vector_type(4)));
typedef short short8_t __attribute__((ext_vector_type(8)));

// ---- bf16 helpers (RNE) ----
__device__ __forceinline__ short f2bf(float v) {
  unsigned u = __float_as_uint(v);
  unsigned r = (u + 0x7fffu + ((u >> 16) & 1u)) >> 16;
  return (short)r;
}
__device__ __forceinline__ float bf2f(short s) {
  return __uint_as_float(((unsigned)(unsigned short)s) << 16);
}

__device__ __forceinline__ float log_cosh_f(float t) {
  float a = fabsf(t);
  return a + __logf(1.f + __expf(-2.f * a)) - 0.6931471805599453f;
}

__device__ __forceinline__ float wave_sum(float v) {
  #pragma unroll
  for (int d = 1; d < 64; d <<= 1) v += __shfl_xor(v, d, 64);
  return v;
}

__device__ __forceinline__ void load_lds16(const void* g, void* l) {
  __builtin_amdgcn_global_load_lds(
      (const __attribute__((address_space(1))) void*)g,
      (__attribute__((address_space(3))) void*)l, 16, 0, 0);
}

// ============================================================
// Kernel 1: build A (bf16 features) + bias -> out[b]
// A row layout (K = 1856):
//  [0,1152)    x
//  [1152,1728) cv0
//  [1728,1752) cv1_hi   [1752,1776) cv1_lo   [1776,1792) zero
//  [1792,1816) cv2_hi   [1816,1840) cv2_lo   [1840,1856) zero
// ============================================================
__global__ __launch_bounds__(256) void build_a_kernel(
    const float* __restrict__ x, const float* __restrict__ vb,
    const float* __restrict__ cb0, const float* __restrict__ cb1,
    const float* __restrict__ cb2,
    const int* __restrict__ idx0, const int* __restrict__ idx1,
    const int* __restrict__ idx2,
    short* __restrict__ A, float* __restrict__ out) {
  int b = blockIdx.x, t = threadIdx.x;
  __shared__ float xs[S_];
  __shared__ float red[20];
  float se = 0.f, so = 0.f, s0 = 0.f, s1 = 0.f, s2 = 0.f;
  const float* xr = x + (size_t)b * S_;
  short* Ar = A + (size_t)b * KA;

  for (int i = t; i < S_; i += 256) {
    float v = xr[i];
    xs[i] = v;
    Ar[i] = f2bf(v);
    if (i & 1) so += v; else se += v;
  }
  __syncthreads();

  for (int c = t; c < NP_; c += 256) {
    const int* q = idx0 + c * 4;
    float p = xs[q[0]] * xs[q[1]] * xs[q[2]] * xs[q[3]];
    s0 += p;
    Ar[S_ + c] = f2bf(p);
  }
  if (t < L_) {
    const int* q = idx1 + t * L_;
    float p = 1.f;
    #pragma unroll
    for (int j = 0; j < L_; ++j) p *= xs[q[j]];
    s1 = p;
    short hi = f2bf(p);
    Ar[1728 + t] = hi;
    Ar[1752 + t] = f2bf(p - bf2f(hi));
  }
  if (t >= 32 && t < 32 + L_) {
    int l = t - 32;
    const int* q = idx2 + l * L_;
    float p = 1.f;
    #pragma unroll
    for (int j = 0; j < L_; ++j) p *= xs[q[j]];
    s2 = p;
    short hi = f2bf(p);
    Ar[1792 + l] = hi;
    Ar[1816 + l] = f2bf(p - bf2f(hi));
  }
  if (t >= 64 && t < 80) Ar[1776 + (t - 64)] = 0;
  if (t >= 80 && t < 96) Ar[1840 + (t - 80)] = 0;

  se = wave_sum(se); so = wave_sum(so);
  s0 = wave_sum(s0); s1 = wave_sum(s1); s2 = wave_sum(s2);
  int w = t >> 6;
  if ((t & 63) == 0) {
    red[w] = se; red[4 + w] = so; red[8 + w] = s0;
    red[12 + w] = s1; red[16 + w] = s2;
  }
  __syncthreads();
  if (t == 0) {
    float a  = red[0] + red[1] + red[2] + red[3];
    float bb = red[4] + red[5] + red[6] + red[7];
    float c0 = red[8] + red[9] + red[10] + red[11];
    float c1 = red[12] + red[13] + red[14] + red[15];
    float c2 = red[16] + red[17] + red[18] + red[19];
    out[b] = vb[0] * a + vb[1] * bb + cb0[0] * c0 + cb1[0] * c1 + cb2[0] * c2;
  }
}

// ============================================================
// Kernel 2: gather weights.
// Wt[n][k], n = g*16 + f, k in [0,KA). Wlt[n][0:64) = loop0 block,
// Wlt[n][64:128) = loop1 block.
// ============================================================
__global__ __launch_bounds__(256) void build_w_kernel(
    const float* __restrict__ symm_kernel, const int* __restrict__ symmetries,
    const float* __restrict__ c0k, const int* __restrict__ c0s,
    const float* __restrict__ c1k, const int* __restrict__ c1s,
    const float* __restrict__ c2k, const int* __restrict__ c2s,
    const float* __restrict__ l0k, const float* __restrict__ l1k,
    short* __restrict__ Wt, short* __restrict__ Wlt) {
  const int CHUNKS = KV / 8;  // 248
  int t = blockIdx.x * 256 + threadIdx.x;
  int n = t / CHUNKS;
  if (n >= NCOL) return;
  int ch = t - n * CHUNKS;
  int g = n >> 4, f = n & 15;
  int k0 = ch * 8;
  short8_t pack;
  #pragma unroll
  for (int j = 0; j < 8; ++j) {
    int k = k0 + j;
    float val;
    if (k < 1152) {
      val = symm_kernel[f * S_ + symmetries[g * S_ + k]];
    } else if (k < 1728) {
      int c = k - 1152;
      val = c0k[f * NP_ + c0s[g * NP_ + c]];
    } else if (k < 1792) {
      int c = k - 1728;
      val = (c < 48) ? c1k[f * L_ + c1s[g * L_ + (c < 24 ? c : c - 24)]] : 0.f;
    } else if (k < 1856) {
      int c = k - 1792;
      val = (c < 48) ? c2k[f * L_ + c2s[g * L_ + (c < 24 ? c : c - 24)]] : 0.f;
    } else if (k < 1920) {
      int c = k - 1856;
      val = (c < 48) ? l0k[f * L_ + c1s[g * L_ + (c < 24 ? c : c - 24)]] : 0.f;
    } else {
      int c = k - 1920;
      val = (c < 48) ? l1k[f * L_ + c2s[g * L_ + (c < 24 ? c : c - 24)]] : 0.f;
    }
    pack[j] = f2bf(val);
  }
  if (k0 < KA) *(short8_t*)(Wt + (size_t)n * KA + k0) = pack;
  else         *(short8_t*)(Wlt + (size_t)n * 128 + (k0 - KA)) = pack;
}

// ============================================================
// Kernel 3: fused GEMM + log_cosh reduction.
// 128x128 tile, BK=64, 4 waves (2x2), 16x16x32 bf16 MFMA.
// r4 post-mortem: 2-phase __syncthreads() loop exposed full staging
// latency every K-step (vmcnt(0) drain, 1 block/CU) -> 3900 cyc/step.
// This round: 3-buffer async pipeline, 2 tiles in flight:
//   iter t: stage(tile t+2 -> buf (t+2)%3); vmcnt(16); s_barrier;
//           compute(buf t%3); s_barrier
// Raw s_barrier (no implicit drain) + counted vmcnt (T4): loads get
// ~2 iterations to land. WAR on buf (t+2)%3 is barrier-separated
// (last read at iter t-1). ds_reads drain via MFMA data deps before
// bar2; sched_barrier(0) fences motion (rule 18).
// XOR swizzle (0 conflicts, verified r2) + XCD supertile unchanged.
// ============================================================
__global__ __launch_bounds__(256) void gemm_fused(
    const short* __restrict__ A, const short* __restrict__ Wt,
    const short* __restrict__ Wlt,
    const float* __restrict__ hidden_bias, const float* __restrict__ l0hb,
    const float* __restrict__ l1hb, float* __restrict__ out) {
  __shared__ short Als[3][128 * 64];
  __shared__ short Bls[3][128 * 64];
  const int tid = threadIdx.x;
  const int w = tid >> 6, lane = tid & 63;
  const int wm = w >> 1, wn = w & 1;
  const int lr = lane & 15, lg = lane >> 4;

  // XCD-aware tile mapping (bijective: 8*576 = 4608)
  const int bid = blockIdx.x;
  const int xcd = bid & 7;
  const int idx = bid >> 3;         // 0..575
  const int st  = idx >> 6;         // supertile column 0..8
  const int u   = idx & 63;
  const int m0 = (xcd * 8 + (u & 7)) * 128;
  const int n0 = (st * 8 + (u >> 3)) * 128;

  // staging geometry: chunk p = i*256 + tid -> row = i*32 + (tid>>3), slot = tid&7
  const int srow = tid >> 3;
  const int scol = ((tid & 7) ^ (srow & 7)) * 16;  // pre-swizzled source byte offset

  f32x4 acc[4][4];
  float rs[4][4];
  #pragma unroll
  for (int i = 0; i < 4; ++i)
    #pragma unroll
    for (int j = 0; j < 4; ++j) {
      #pragma unroll
      for (int q = 0; q < 4; ++q) acc[i][j][q] = 0.f;
      rs[i][j] = 0.f;
    }

  const char* Abase = (const char*)A + (size_t)m0 * (KA * 2);
  const char* Wbase = (const char*)Wt + (size_t)n0 * (KA * 2);
  const char* Lbase = (const char*)Wlt + (size_t)n0 * 256;

  // stage one 128x64 A-tile + B-tile into buf (8 load_lds16 per thread/wave)
  auto stage = [&](int buf, size_t aOff, const char* bSrc, size_t bStride, size_t bOff) {
    #pragma unroll
    for (int i = 0; i < 4; ++i) {
      int row = i * 32 + srow;
      load_lds16(Abase + (size_t)row * (KA * 2) + aOff + scol,
                 (char*)&Als[buf][0] + (i * 256 + w * 64) * 16);
      load_lds16(bSrc + (size_t)row * bStride + bOff + scol,
                 (char*)&Bls[buf][0] + (i * 256 + w * 64) * 16);
    }
  };

  // swizzled bf16 index for fragment read: row*64 + ((chunk ^ (row&7)) * 8)
  auto compute = [&](int buf) {
    #pragma unroll
    for (int kk = 0; kk < 2; ++kk) {
      short8_t af[4], wf[4];
      #pragma unroll
      for (int mi = 0; mi < 4; ++mi) {
        int row = wm * 64 + mi * 16 + lr;
        af[mi] = *(const short8_t*)&Als[buf][row * 64 + (((kk * 4 + lg) ^ (lr & 7)) * 8)];
      }
      #pragma unroll
      for (int ni = 0; ni < 4; ++ni) {
        int row = wn * 64 + ni * 16 + lr;
        wf[ni] = *(const short8_t*)&Bls[buf][row * 64 + (((kk * 4 + lg) ^ (lr & 7)) * 8)];
      }
      #pragma unroll
      for (int mi = 0; mi < 4; ++mi)
        #pragma unroll
        for (int ni = 0; ni < 4; ++ni)
          acc[mi][ni] = __builtin_amdgcn_mfma_f32_16x16x32_bf16(af[mi], wf[ni], acc[mi][ni], 0, 0, 0);
    }
  };

  const size_t WS = (size_t)(KA * 2);  // W row stride (bytes)

  // ---- prologue: 2 tiles in flight ----
  stage(0, 0, Wbase, WS, 0);
  stage(1, 128, Wbase, WS, 128);

  // ---- async main K loop: 29 tiles ----
  int bc = 0;  // compute buffer = t % 3
  for (int t = 0; t < 29; ++t) {
    if (t + 2 <= 28) {
      int bs = bc + 2; if (bs >= 3) bs -= 3;     // (t+2) % 3
      stage(bs, (size_t)(t + 2) * 128, Wbase, WS, (size_t)(t + 2) * 128);
    }
    __builtin_amdgcn_sched_barrier(0);
    if (t < 27)       asm volatile("s_waitcnt vmcnt(16)" ::: "memory");
    else if (t == 27) asm volatile("s_waitcnt vmcnt(8)" ::: "memory");
    else              asm volatile("s_waitcnt vmcnt(0)" ::: "memory");
    __builtin_amdgcn_sched_barrier(0);
    __builtin_amdgcn_s_barrier();                 // all waves: tile t staged
    __builtin_amdgcn_sched_barrier(0);
    compute(bc);
    __builtin_amdgcn_sched_barrier(0);
    __builtin_amdgcn_s_barrier();                 // all reads done before overwrite
    __builtin_amdgcn_sched_barrier(0);
    bc = bc + 1; if (bc >= 3) bc = 0;
  }

  // ---- issue loop-pass stages early; theta log_cosh hides their latency ----
  stage(0, (size_t)1728 * 2, Lbase, 256, 0);    // cv1 block x loop0 weights
  stage(1, (size_t)1792 * 2, Lbase, 256, 128);  // cv2 block x loop1 weights

  // theta epilogue
  {
    float hb = hidden_bias[lr];  // f = col & 15 = lr
    #pragma unroll
    for (int mi = 0; mi < 4; ++mi)
      #pragma unroll
      for (int i = 0; i < 4; ++i) {
        float s = 0.f;
        #pragma unroll
        for (int ni = 0; ni < 4; ++ni) s += log_cosh_f(acc[mi][ni][i] + hb);
        rs[mi][i] += s;
      }
  }
  __syncthreads();  // full drain: loop-pass tiles staged & visible

  // loop-correlator passes (no barrier needed between: disjoint bufs, no writes)
  #pragma unroll
  for (int pass = 0; pass < 2; ++pass) {
    #pragma unroll
    for (int i = 0; i < 4; ++i)
      #pragma unroll
      for (int j = 0; j < 4; ++j)
        #pragma unroll
        for (int q = 0; q < 4; ++q) acc[i][j][q] = 0.f;

    compute(pass);

    float lb = (pass == 0 ? l0hb : l1hb)[lr];
    #pragma unroll
    for (int mi = 0; mi < 4; ++mi)
      #pragma unroll
      for (int i = 0; i < 4; ++i) {
        float s = 0.f;
        #pragma unroll
        for (int ni = 0; ni < 4; ++ni) s += log_cosh_f(acc[mi][ni][i] + lb);
        rs[mi][i] += s;
      }
  }

  // reduce across the 16 lanes that share each row, then atomicAdd
  #pragma unroll
  for (int mi = 0; mi < 4; ++mi)
    #pragma unroll
    for (int i = 0; i < 4; ++i) {
      float v = rs[mi][i];
      v += __shfl_xor(v, 1, 64);
      v += __shfl_xor(v, 2, 64);
      v += __shfl_xor(v, 4, 64);
      v += __shfl_xor(v, 8, 64);
      if (lr == 0) atomicAdd(&out[m0 + wm * 64 + mi * 16 + lg * 4 + i], v);
    }
}

// ============================================================
extern "C" void kernel_launch(void* const* d_in, const int* in_sizes, int n_in,
                              void* d_out, int out_size, void* d_ws, size_t ws_size,
                              hipStream_t stream) {
  const float* x            = (const float*)d_in[0];
  const float* hidden_bias  = (const float*)d_in[1];
  const float* symm_kernel  = (const float*)d_in[2];
  const float* visible_bias = (const float*)d_in[3];
  const float* corr0_bias   = (const float*)d_in[4];
  const float* corr0_kernel = (const float*)d_in[5];
  const float* corr1_bias   = (const float*)d_in[6];
  const float* corr1_kernel = (const float*)d_in[7];
  const float* corr2_bias   = (const float*)d_in[8];
  const float* corr2_kernel = (const float*)d_in[9];
  const float* l0hb         = (const float*)d_in[10];
  const float* l0k          = (const float*)d_in[11];
  const float* l1hb         = (const float*)d_in[12];
  const float* l1k          = (const float*)d_in[13];
  const int* symmetries     = (const int*)d_in[14];
  const int* idx0           = (const int*)d_in[15];
  const int* c0s            = (const int*)d_in[16];
  const int* idx1           = (const int*)d_in[17];
  const int* c1s            = (const int*)d_in[18];
  const int* idx2           = (const int*)d_in[19];
  const int* c2s            = (const int*)d_in[20];

  // workspace layout
  short* A   = (short*)d_ws;                                  // 8192*1856*2   = 30,408,704 B
  short* Wt  = (short*)((char*)d_ws + 30408704);              // 9216*1856*2   = 34,209,792 B
  short* Wlt = (short*)((char*)d_ws + 64618496);              // 9216*128*2    =  2,359,296 B
  float* out = (float*)d_out;

  build_a_kernel<<<B_, 256, 0, stream>>>(x, visible_bias, corr0_bias, corr1_bias,
                                         corr2_bias, idx0, idx1, idx2, A, out);
  build_w_kernel<<<(NCOL * (KV / 8)) / 256, 256, 0, stream>>>(
      symm_kernel, symmetries, corr0_kernel, c0s, corr1_kernel, c1s,
      corr2_kernel, c2s, l0k, l1k, Wt, Wlt);
  gemm_fused<<<4608, 256, 0, stream>>>(
      A, Wt, Wlt, hidden_bias, l0hb, l1hb, out);
}